// Round 9
// baseline (221.778 us; speedup 1.0000x reference)
//
#include <hip/hip_runtime.h>

#define BB 4
#define HH 1024
#define WW 1024
#define K2 9
#define PAD 1

#define R   12            // halo radius (covers ~6 sigma offsets)
#define TW  64            // tile width
#define TH  16            // tile height (4 rows, one per wave per iteration)
#define RW  (TW + 2*R)    // 88
#define RH  (TH + 2*R)    // 40
#define RSZ (RW * RH)     // 3520 floats = 14080 B

#define NSLOT  27                 // stream dwords per pixel (9 wt + 9 dy + 9 dx)
#define SBUF_N (NSLOT * 256)      // floats per buffer (per 256-thread block row-set)

// async global->LDS DMA, 4 bytes/lane; LDS dest = wave-uniform base + lane*4
__device__ __forceinline__ void gload_lds(const float* g, float* l) {
    __builtin_amdgcn_global_load_lds((const __attribute__((address_space(1))) void*)g,
                                     (__attribute__((address_space(3))) void*)l,
                                     4, 0, 0);
}

__global__ __launch_bounds__(256) void dcn_kernel(
    const float* __restrict__ init_dem,   // [B,1,H,W]
    const float* __restrict__ weight,     // [B,K2,H,W]
    const float* __restrict__ offset,     // [B,2*K2,H,W]
    const float* __restrict__ wk,         // [K2]
    const float* __restrict__ bias,       // [1]
    float* __restrict__ out)              // [B,1,H,W]
{
    __shared__ float region[RSZ];
    __shared__ float sbuf[2 * SBUF_N];    // double-buffered stream staging (55296 B)

    const int HW = HH * WW;

    // batch pinned to an XCD pair (blockIdx % 8 -> XCD heuristic)
    int i    = blockIdx.x;
    int b    = (i & 7) >> 1;
    int widx = ((i >> 3) << 1) | (i & 1);     // 0..1023, bijective
    int tile_w = widx & 15;                   // W/TW = 16
    int tile_h = widx >> 4;                   // H/TH = 64
    int w0 = tile_w * TW;
    int h0 = tile_h * TH;

    const float* img = init_dem + (size_t)b * HW;
    const float* wbase = weight + (size_t)b * K2 * HW;
    const float* obase = offset + (size_t)b * 2 * K2 * HW;

    const int tid  = threadIdx.x;
    const int tx   = tid & 63;     // lane
    const int wv   = tid >> 6;     // wave id = row within 4-row group

    // scalar params into registers before any barriers
    float wgt[K2];
#pragma unroll
    for (int k = 0; k < K2; ++k) wgt[k] = wk[k];
    const float bval = bias[0];

    // ---- prologue: issue DMA batch for iteration 0 into buffer 0 ----
    // (in flight during region staging; the staging barrier drains it)
#define ISSUE_BATCH(P, BF) do {                                                   \
        int rem_ = (h0 + wv + (P) * 4) * WW + w0 + tx;                            \
        const float* wq_ = wbase + rem_;                                          \
        const float* oq_ = obase + rem_;                                          \
        _Pragma("unroll")                                                         \
        for (int kk = 0; kk < K2; ++kk) {                                         \
            gload_lds(wq_ + (size_t)kk * HW,           &sbuf[(BF) * SBUF_N + ((3 * kk + 0) * 4 + wv) * 64]); \
            gload_lds(oq_ + (size_t)(2 * kk) * HW,     &sbuf[(BF) * SBUF_N + ((3 * kk + 1) * 4 + wv) * 64]); \
            gload_lds(oq_ + (size_t)(2 * kk + 1) * HW, &sbuf[(BF) * SBUF_N + ((3 * kk + 2) * 4 + wv) * 64]); \
        }                                                                         \
    } while (0)

    ISSUE_BATCH(0, 0);

    // ---- stage image region (halo included, zeros outside image) ----
#pragma unroll
    for (int it = 0; it < (RSZ + 255) / 256; ++it) {
        int e = tid + it * 256;
        if (e < RSZ) {
            int r = e / RW;
            int c = e - r * RW;
            int gy = h0 - R + r;
            int gx = w0 - R + c;
            float v = 0.f;
            if ((unsigned)gy < (unsigned)HH && (unsigned)gx < (unsigned)WW)
                v = img[gy * WW + gx];
            region[e] = v;
        }
    }
    __syncthreads();   // compiler emits vmcnt(0): batch 0 is complete here

    const float fx = (float)(tx + R - PAD);

    for (int p = 0; p < 4; ++p) {
        // pipeline: issue next row-set's streams before computing this one
        if (p == 0)      ISSUE_BATCH(1, 1);
        else if (p == 1) ISSUE_BATCH(2, 0);
        else if (p == 2) ISSUE_BATCH(3, 1);

        if (p > 0) {
            // leave the just-issued 27 DMAs in flight; ensure batch p landed
            if (p < 3) asm volatile("s_waitcnt vmcnt(27)" ::: "memory");
            else       asm volatile("s_waitcnt vmcnt(0)"  ::: "memory");
        }

        const float* sb = &sbuf[(p & 1) * SBUF_N];
        const int h   = h0 + wv + p * 4;
        const int rem = h * WW + w0 + tx;
        const float fy = (float)(wv + p * 4 + R - PAD);

        float accA = 0.f;   // sum samp*wk*wt
        float accB = 0.f;   // sum samp*wk
        float msum = 0.f;   // sum wt

#pragma unroll
        for (int k = 0; k < K2; ++k) {
            const int ky = k / 3, kx = k % 3;

            float wtv = sb[((3 * k + 0) * 4 + wv) * 64 + tx];
            float dyv = sb[((3 * k + 1) * 4 + wv) * 64 + tx];
            float dxv = sb[((3 * k + 2) * 4 + wv) * 64 + tx];
            msum += wtv;

            float ysl = (fy + (float)ky) + dyv;
            float xsl = (fx + (float)kx) + dxv;

            float y0f = floorf(ysl);
            float x0f = floorf(xsl);
            float wy1 = ysl - y0f;
            float wx1 = xsl - x0f;
            float wy0 = 1.f - wy1;
            float wx0 = 1.f - wx1;

            int y0l = (int)y0f;
            int x0l = (int)x0f;

            float v00, v01, v10, v11;
            if (((unsigned)y0l < (unsigned)(RH - 1)) &
                ((unsigned)x0l < (unsigned)(RW - 1))) {
                int base = y0l * RW + x0l;
                v00 = region[base];
                v10 = region[base + RW];
                v01 = region[base + 1];
                v11 = region[base + RW + 1];
            } else {
                int y0g = y0l + (h0 - R);
                int x0g = x0l + (w0 - R);
                int y1g = y0g + 1;
                int x1g = x0g + 1;
                bool y0v = (y0g >= 0) & (y0g < HH);
                bool y1v = (y1g >= 0) & (y1g < HH);
                bool x0v = (x0g >= 0) & (x0g < WW);
                bool x1v = (x1g >= 0) & (x1g < WW);
                int yc0 = min(max(y0g, 0), HH - 1);
                int yc1 = min(max(y1g, 0), HH - 1);
                int xc0 = min(max(x0g, 0), WW - 1);
                int xc1 = min(max(x1g, 0), WW - 1);
                v00 = (y0v & x0v) ? img[(size_t)yc0 * WW + xc0] : 0.f;
                v01 = (y0v & x1v) ? img[(size_t)yc0 * WW + xc1] : 0.f;
                v10 = (y1v & x0v) ? img[(size_t)yc1 * WW + xc0] : 0.f;
                v11 = (y1v & x1v) ? img[(size_t)yc1 * WW + xc1] : 0.f;
            }

            float samp = wy0 * (wx0 * v00 + wx1 * v01)
                       + wy1 * (wx0 * v10 + wx1 * v11);
            float sw = samp * wgt[k];
            accA += sw * wtv;
            accB += sw;
        }

        float resid = region[(wv + p * 4 + R) * RW + (tx + R)];
        float rres  = accA - msum * (1.0f / K2) * accB + bval + resid;
        __builtin_nontemporal_store(rres, out + (size_t)b * HW + rem);
    }
#undef ISSUE_BATCH
}

extern "C" void kernel_launch(void* const* d_in, const int* in_sizes, int n_in,
                              void* d_out, int out_size, void* d_ws, size_t ws_size,
                              hipStream_t stream) {
    const float* init_dem = (const float*)d_in[0];
    const float* weight   = (const float*)d_in[1];
    const float* offset   = (const float*)d_in[2];
    const float* wk       = (const float*)d_in[3];
    const float* bias     = (const float*)d_in[4];
    float* out            = (float*)d_out;

    const int nblocks = BB * (WW / TW) * (HH / TH);   // 4*16*64 = 4096
    dcn_kernel<<<dim3(nblocks), dim3(256), 0, stream>>>(init_dem, weight, offset, wk, bias, out);
}

// Round 10
// 106.153 us; speedup vs baseline: 2.0892x; 2.0892x over previous
//
#include <hip/hip_runtime.h>

#define BB 4
#define HH 1024
#define WW 1024
#define K2 9
#define PAD 1

#define R   12            // halo radius (covers ~6 sigma offsets)
#define TW  64            // tile width
#define TH  8             // tile height (2 rows per thread)
#define RW  (TW + 2*R)    // 88
#define RH  (TH + 2*R)    // 32 image rows in halo
#define R2H (RH - 1)      // 31 paired rows
#define RSZ (RW * R2H)    // 2728 float2 = 21824 B

typedef float f32x2 __attribute__((ext_vector_type(2)));

__global__ __launch_bounds__(256) void dcn_kernel(
    const float* __restrict__ init_dem,   // [B,1,H,W]
    const float* __restrict__ weight,     // [B,K2,H,W]
    const float* __restrict__ offset,     // [B,2*K2,H,W]
    const float* __restrict__ wk,         // [K2]
    const float* __restrict__ bias,       // [1]
    float* __restrict__ out)              // [B,1,H,W]
{
    __shared__ f32x2 region2[RSZ];        // (img[r][c], img[r+1][c])

    const int HW = HH * WW;

    // batch pinned to an XCD pair (blockIdx % 8 -> XCD heuristic)
    int i    = blockIdx.x;
    int b    = (i & 7) >> 1;
    int widx = ((i >> 3) << 1) | (i & 1);     // 0 .. 2047, bijective
    int tile_w = widx & 15;                   // W/TW = 16
    int tile_h = widx >> 4;                   // H/TH = 128
    int w0 = tile_w * TW;
    int h0 = tile_h * TH;

    const float* img = init_dem + (size_t)b * HW;

    // ---- stage paired-row region (halo included, zeros outside image) ----
    int tid = threadIdx.x;
#pragma unroll
    for (int it = 0; it < (RSZ + 255) / 256; ++it) {
        int e = tid + it * 256;
        if (e < RSZ) {
            int r = e / RW;
            int c = e - r * RW;
            int gy = h0 - R + r;
            int gx = w0 - R + c;
            float v0 = 0.f, v1 = 0.f;
            if ((unsigned)gx < (unsigned)WW) {
                if ((unsigned)gy < (unsigned)HH)
                    v0 = img[gy * WW + gx];
                if ((unsigned)(gy + 1) < (unsigned)HH)
                    v1 = img[(gy + 1) * WW + gx];
            }
            f32x2 pr; pr[0] = v0; pr[1] = v1;
            region2[e] = pr;
        }
    }
    __syncthreads();

    const int tx = tid & 63;
    const int ty = tid >> 6;
    const float bval = bias[0];

    float wgt[K2];
#pragma unroll
    for (int k = 0; k < K2; ++k) wgt[k] = wk[k];

#pragma unroll
    for (int p = 0; p < 2; ++p) {
        int h = h0 + ty + p * 4;
        int w = w0 + tx;
        int rem = h * WW + w;

        const float* wq = weight + (size_t)b * K2 * HW + rem;
        const float* oq = offset + (size_t)b * 2 * K2 * HW + rem;

        // batch all 27 stream loads (kept in flight together)
        float wt[K2], dy[K2], dx[K2];
        float wsum = 0.f;
#pragma unroll
        for (int k = 0; k < K2; ++k) {
            wt[k] = __builtin_nontemporal_load(wq + (size_t)k * HW);
            dy[k] = __builtin_nontemporal_load(oq + (size_t)(2 * k) * HW);
            dx[k] = __builtin_nontemporal_load(oq + (size_t)(2 * k + 1) * HW);
            wsum += wt[k];
        }
        const float mean = wsum * (1.0f / K2);

        // local (region-space) coords
        const float fy = (float)(ty + p * 4 + R - PAD);
        const float fx = (float)(tx + R - PAD);

        float acc = 0.f;
#pragma unroll
        for (int k = 0; k < K2; ++k) {
            const int ky = k / 3, kx = k % 3;

            float ysl = (fy + (float)ky) + dy[k];
            float xsl = (fx + (float)kx) + dx[k];

            float y0f = floorf(ysl);
            float x0f = floorf(xsl);
            float wy1 = ysl - y0f;
            float wx1 = xsl - x0f;
            float wy0 = 1.f - wy1;
            float wx0 = 1.f - wx1;

            int y0l = (int)y0f;
            int x0l = (int)x0f;

            float v00, v01, v10, v11;
            if (((unsigned)y0l < (unsigned)R2H) &
                ((unsigned)x0l < (unsigned)(RW - 1))) {
                int base = y0l * RW + x0l;
                // one ds_read2_b64: (v00,v10) and (v01,v11)
                f32x2 a  = region2[base];
                f32x2 cc = region2[base + 1];
                v00 = a[0];  v10 = a[1];
                v01 = cc[0]; v11 = cc[1];
            } else {
                int y0g = y0l + (h0 - R);
                int x0g = x0l + (w0 - R);
                int y1g = y0g + 1;
                int x1g = x0g + 1;
                bool y0v = (y0g >= 0) & (y0g < HH);
                bool y1v = (y1g >= 0) & (y1g < HH);
                bool x0v = (x0g >= 0) & (x0g < WW);
                bool x1v = (x1g >= 0) & (x1g < WW);
                int yc0 = min(max(y0g, 0), HH - 1);
                int yc1 = min(max(y1g, 0), HH - 1);
                int xc0 = min(max(x0g, 0), WW - 1);
                int xc1 = min(max(x1g, 0), WW - 1);
                v00 = (y0v & x0v) ? img[(size_t)yc0 * WW + xc0] : 0.f;
                v01 = (y0v & x1v) ? img[(size_t)yc0 * WW + xc1] : 0.f;
                v10 = (y1v & x0v) ? img[(size_t)yc1 * WW + xc0] : 0.f;
                v11 = (y1v & x1v) ? img[(size_t)yc1 * WW + xc1] : 0.f;
            }

            float samp = wy0 * (wx0 * v00 + wx1 * v01)
                       + wy1 * (wx0 * v10 + wx1 * v11);
            acc += samp * (wt[k] - mean) * wgt[k];
        }

        float resid = region2[(ty + p * 4 + R) * RW + (tx + R)][0];
        float rres  = acc + bval + resid;
        __builtin_nontemporal_store(rres, out + (size_t)b * HW + rem);
    }
}

extern "C" void kernel_launch(void* const* d_in, const int* in_sizes, int n_in,
                              void* d_out, int out_size, void* d_ws, size_t ws_size,
                              hipStream_t stream) {
    const float* init_dem = (const float*)d_in[0];
    const float* weight   = (const float*)d_in[1];
    const float* offset   = (const float*)d_in[2];
    const float* wk       = (const float*)d_in[3];
    const float* bias     = (const float*)d_in[4];
    float* out            = (float*)d_out;

    const int nblocks = BB * (WW / TW) * (HH / TH);   // 4*16*128 = 8192
    dcn_kernel<<<dim3(nblocks), dim3(256), 0, stream>>>(init_dem, weight, offset, wk, bias, out);
}